// Round 10
// baseline (6320.274 us; speedup 1.0000x reference)
//
#include <hip/hip_runtime.h>
#include <cstdint>
#include <cstddef>

#define IN_F  4096
#define OUT_F 16384
#define NROWS 8192   // 2*4096 tokens
#define NKT   64     // K-tiles of 64 bytes

typedef __attribute__((ext_vector_type(4)))  int int32x4;
typedef __attribute__((ext_vector_type(16))) int int32x16;

// async global->LDS, 16B/lane (dest = wave-uniform base, HW adds lane*16)
__device__ __forceinline__ void gload_lds16(const void* g, void* s) {
    __builtin_amdgcn_global_load_lds((const __attribute__((address_space(1))) void*)g,
                                     (__attribute__((address_space(3))) void*)s,
                                     16, 0, 0);
}

// ---------------------------------------------------------------------------
// Layouts (fragment-major, shared by producers and GEMM staging):
//   xqS: [mtile 32][kt 64][c 4][row 256][16B]   c = ksub*2+kh, k = kt*64+c*16..+16
//   wtS: [ntile 64][kt 64][c 4][col 256][16B]
// ---------------------------------------------------------------------------

// Kernel 1: weight [K=4096][N=16384] int32 -> wtS (narrow + transpose + tile)
__global__ __launch_bounds__(256) void transpose_kernel(const int* __restrict__ w,
                                                        uint8_t* __restrict__ wtS) {
    __shared__ uint8_t tile[64][68];
    const int t  = threadIdx.x;
    const int nb = blockIdx.x * 64;
    const int kt = blockIdx.y;          // K-tile = 64 k-rows
    const int kb = kt * 64;

#pragma unroll
    for (int p = 0; p < 4; ++p) {
        const int r = p * 16 + (t >> 4);
        const int c4 = t & 15;
        int4 u = *reinterpret_cast<const int4*>(w + (size_t)(kb + r) * OUT_F + nb + c4 * 4);
        uint32_t packed = (uint32_t)(u.x & 255) | ((uint32_t)(u.y & 255) << 8)
                        | ((uint32_t)(u.z & 255) << 16) | ((uint32_t)(u.w & 255) << 24);
        *reinterpret_cast<uint32_t*>(&tile[r][c4 * 4]) = packed;
    }
    __syncthreads();

    const int col = t >> 2;             // 0..63
    const int c   = t & 3;              // ksub*2+kh
    uint4 o;
    uint32_t* op = reinterpret_cast<uint32_t*>(&o);
#pragma unroll
    for (int j = 0; j < 4; ++j) {
        const int kk = c * 16 + j * 4;
        op[j] = (uint32_t)tile[kk][col] | ((uint32_t)tile[kk + 1][col] << 8)
              | ((uint32_t)tile[kk + 2][col] << 16) | ((uint32_t)tile[kk + 3][col] << 24);
    }
    const int ntile = nb >> 8;
    const int colg  = (nb & 255) + col;
    *reinterpret_cast<uint4*>(wtS + (((size_t)ntile * NKT + kt) * 4 + c) * 4096 + colg * 16) = o;
}

// Kernel 2: per-row dynamic quant -> xqS (fragment-major) + xs
__global__ __launch_bounds__(256) void quant_kernel(const float* __restrict__ x,
                                                    uint8_t* __restrict__ xqS,
                                                    float* __restrict__ xs) {
    const int t = threadIdx.x;
    const int w = t >> 6, l = t & 63;
    const int half = l >> 5, lh = l & 31;
    const int m = blockIdx.x * 8 + w * 2 + half;
    const float* xr = x + (size_t)m * IN_F;

    float am = 0.0f;
#pragma unroll 8
    for (int jj = 0; jj < 32; ++jj) {
        float4 v = reinterpret_cast<const float4*>(xr)[jj * 32 + lh];
        am = fmaxf(am, fmaxf(fmaxf(fabsf(v.x), fabsf(v.y)),
                             fmaxf(fabsf(v.z), fabsf(v.w))));
    }
#pragma unroll
    for (int off = 16; off; off >>= 1) am = fmaxf(am, __shfl_xor(am, off));

    const float scale = fmaxf(am / 127.0f, 1e-12f);
    if (lh == 0) xs[m] = scale;

    const int mtile = m >> 8, mrow = m & 255;
    uint8_t* ob = xqS + (size_t)mtile * (NKT * 16384) + (size_t)mrow * 16;
#pragma unroll
    for (int j = 0; j < 8; ++j) {
        const int k0 = lh * 128 + j * 16;
        const float4* vp = reinterpret_cast<const float4*>(xr + k0);
        uint4 pk;
        uint32_t* pp = reinterpret_cast<uint32_t*>(&pk);
#pragma unroll
        for (int q = 0; q < 4; ++q) {
            float4 v = vp[q];
            float r0 = fminf(127.f, fmaxf(-128.f, rintf(v.x / scale)));
            float r1 = fminf(127.f, fmaxf(-128.f, rintf(v.y / scale)));
            float r2 = fminf(127.f, fmaxf(-128.f, rintf(v.z / scale)));
            float r3 = fminf(127.f, fmaxf(-128.f, rintf(v.w / scale)));
            pp[q] = ((uint32_t)((int)r0 & 255)) | ((uint32_t)((int)r1 & 255) << 8)
                  | ((uint32_t)((int)r2 & 255) << 16) | ((uint32_t)((int)r3 & 255) << 24);
        }
        const int ktk = k0 >> 6;
        const int c   = (k0 >> 4) & 3;
        *reinterpret_cast<uint4*>(ob + ((size_t)ktk * 4 + c) * 4096) = pk;
    }
}

// ---------------------------------------------------------------------------
// Kernel 3: int8 GEMM, 256x256 tile, 4 fat waves (2x2 grid, 128x128/wave,
// acc[4][4]) + **double-buffered 64KB LDS -> 2 blocks/CU (2 waves/SIMD)**.
// Fat waves cut LDS reads to 64KB/K-tile; the co-resident block's waves fill
// both pipes through this block's barriers (cross-block TLP replaces the
// in-block phase overlap that rounds 4-9 couldn't buy).
// ---------------------------------------------------------------------------
__global__ __launch_bounds__(256, 2) void gemm_kernel(const uint8_t* __restrict__ xqS,
                                                      const uint8_t* __restrict__ wtS,
                                                      const float* __restrict__ xs,
                                                      const float* __restrict__ wsc,
                                                      const float* __restrict__ bias,
                                                      float* __restrict__ out) {
    __shared__ uint8_t lds[65536];
    uint8_t* ldsA = lds;            // 2 bufs * 16KB
    uint8_t* ldsB = lds + 32768;    // 2 bufs * 16KB

    const int t    = threadIdx.x;
    const int lane = t & 63;
    const int wid  = t >> 6;                   // 0..3
    const int wm   = wid >> 1, wn = wid & 1;   // wave tile: 128 rows x 128 cols

    // XCD-aware mapping (round 8: FETCH 1.08GB -> 394MB):
    // XCD x owns mt rows 4x..4x+3; nt-outer so 4 neighbors share a B panel.
    const int xcd = blockIdx.x & 7;
    const int i   = blockIdx.x >> 3;           // 0..255 local on this XCD
    const int mt  = xcd * 4 + (i & 3);         // 0..31
    const int nt  = i >> 2;                    // 0..63

    const uint8_t* aBase = xqS + (size_t)mt * (NKT * 16384);
    const uint8_t* bBase = wtS + (size_t)nt * (NKT * 16384);
    const int t16  = t * 16;                   // 256 thr * 16B = 4KB per gload
    const int wofs = wid * 1024;

    const int aRd0 = (lane >> 5) * 4096 + wm * 2048 + (lane & 31) * 16;
    const int bRd0 = (lane >> 5) * 4096 + wn * 2048 + (lane & 31) * 16;

    int32x16 acc[4][4] = {};
    int32x4 af0[4], bf0[4], af1[4], bf1[4];

    // prologue: stage K-tile 0 into buf 0
#pragma unroll
    for (int p = 0; p < 4; ++p) {
        gload_lds16(aBase + p * 4096 + t16, ldsA + p * 4096 + wofs);
        gload_lds16(bBase + p * 4096 + t16, ldsB + p * 4096 + wofs);
    }
    asm volatile("s_waitcnt vmcnt(0)" ::: "memory");
    __builtin_amdgcn_s_barrier();
    __builtin_amdgcn_sched_barrier(0);

    for (int kt = 0; kt < NKT; ++kt) {
        const int q  = (kt & 1) * 16384;
        const int qn = ((kt + 1) & 1) * 16384;

        // 1. stage tile kt+1 into the other buffer (its readers — tile kt-1 —
        //    drained before the last barrier via lgkmcnt(0))
        if (kt < NKT - 1) {
            const size_t srcn = (size_t)(kt + 1) * 16384;
#pragma unroll
            for (int p = 0; p < 4; ++p) {
                gload_lds16(aBase + srcn + p * 4096 + t16, ldsA + qn + p * 4096 + wofs);
                gload_lds16(bBase + srcn + p * 4096 + t16, ldsB + qn + p * 4096 + wofs);
            }
        }

        // 2. issue all 16 ds_reads of tile kt (s=0 -> f0, s=1 -> f1)
#pragma unroll
        for (int mr = 0; mr < 4; ++mr)
            af0[mr] = *reinterpret_cast<const int32x4*>(ldsA + q + aRd0 + mr * 512);
#pragma unroll
        for (int nr = 0; nr < 4; ++nr)
            bf0[nr] = *reinterpret_cast<const int32x4*>(ldsB + q + bRd0 + nr * 512);
#pragma unroll
        for (int mr = 0; mr < 4; ++mr)
            af1[mr] = *reinterpret_cast<const int32x4*>(ldsA + q + 8192 + aRd0 + mr * 512);
#pragma unroll
        for (int nr = 0; nr < 4; ++nr)
            bf1[nr] = *reinterpret_cast<const int32x4*>(ldsB + q + 8192 + bRd0 + nr * 512);

        // 3. MFMA on f0 once its 8 reads are in (f1's reads drain underneath;
        //    the other block's waves keep the pipes busy through our stalls)
        asm volatile("s_waitcnt lgkmcnt(8)" ::: "memory");
        __builtin_amdgcn_sched_barrier(0);
        __builtin_amdgcn_s_setprio(1);
#pragma unroll
        for (int mr = 0; mr < 4; ++mr)
#pragma unroll
            for (int nr = 0; nr < 4; ++nr)
                acc[mr][nr] = __builtin_amdgcn_mfma_i32_32x32x32_i8(af0[mr], bf0[nr], acc[mr][nr], 0, 0, 0);
        __builtin_amdgcn_s_setprio(0);

        // 4. MFMA on f1 after all reads drain
        asm volatile("s_waitcnt lgkmcnt(0)" ::: "memory");
        __builtin_amdgcn_sched_barrier(0);
        __builtin_amdgcn_s_setprio(1);
#pragma unroll
        for (int mr = 0; mr < 4; ++mr)
#pragma unroll
            for (int nr = 0; nr < 4; ++nr)
                acc[mr][nr] = __builtin_amdgcn_mfma_i32_32x32x32_i8(af1[mr], bf1[nr], acc[mr][nr], 0, 0, 0);
        __builtin_amdgcn_s_setprio(0);

        // 5. tile boundary: my stage loads landed (issued a full tile ago),
        //    my reads drained (step 4) -> barrier publishes buf kt+1 and
        //    frees buf kt for the next stage.
        if (kt < NKT - 1) {
            asm volatile("s_waitcnt vmcnt(0)" ::: "memory");
            __builtin_amdgcn_s_barrier();
            __builtin_amdgcn_sched_barrier(0);
        }
    }

    // epilogue: C/D 32x32 layout: col = lane&31, row = (g&3)+8*(g>>2)+4*(lane>>5)
    const int row0 = mt * 256 + wm * 128;
    const int col0 = nt * 256 + wn * 128;
#pragma unroll
    for (int mr = 0; mr < 4; ++mr) {
        const int rbase = row0 + mr * 32 + 4 * (lane >> 5);
        float xsv[16];
#pragma unroll
        for (int g = 0; g < 16; ++g)
            xsv[g] = xs[rbase + (g & 3) + 8 * (g >> 2)];
#pragma unroll
        for (int nr = 0; nr < 4; ++nr) {
            const int n = col0 + nr * 32 + (lane & 31);
            const float ws_n = wsc[n];
            const float b_n  = bias[n];
#pragma unroll
            for (int g = 0; g < 16; ++g) {
                const int m = rbase + (g & 3) + 8 * (g >> 2);
                out[(size_t)m * OUT_F + n] = (float)acc[mr][nr][g] * xsv[g] * ws_n + b_n;
            }
        }
    }
}

// ---------------------------------------------------------------------------
extern "C" void kernel_launch(void* const* d_in, const int* in_sizes, int n_in,
                              void* d_out, int out_size, void* d_ws, size_t ws_size,
                              hipStream_t stream) {
    const float* x    = (const float*)d_in[0];
    const int*   wq   = (const int*)d_in[1];     // int8 pushed as int32 [4096][16384]
    const float* wsc  = (const float*)d_in[2];
    const float* bias = (const float*)d_in[3];
    float* out = (float*)d_out;

    uint8_t* ws  = (uint8_t*)d_ws;
    uint8_t* wtS = ws;                                               // 64 MiB
    uint8_t* xqS = ws + (size_t)IN_F * OUT_F;                        // 32 MiB
    float*   xs  = (float*)(ws + (size_t)IN_F * OUT_F + (size_t)NROWS * IN_F);

    transpose_kernel<<<dim3(OUT_F / 64, IN_F / 64), 256, 0, stream>>>(wq, wtS);
    quant_kernel<<<NROWS / 8, 256, 0, stream>>>(x, xqS, xs);
    gemm_kernel<<<(NROWS / 256) * (OUT_F / 256), 256, 0, stream>>>(xqS, wtS, xs, wsc, bias, out);
}

// Round 11
// 782.434 us; speedup vs baseline: 8.0777x; 8.0777x over previous
//
#include <hip/hip_runtime.h>
#include <cstdint>
#include <cstddef>

#define IN_F  4096
#define OUT_F 16384
#define NROWS 8192   // 2*4096 tokens
#define NKT   64     // K-tiles of 64 bytes

typedef __attribute__((ext_vector_type(4)))  int int32x4;
typedef __attribute__((ext_vector_type(16))) int int32x16;

// async global->LDS, 16B/lane (dest = wave-uniform base, HW adds lane*16)
__device__ __forceinline__ void gload_lds16(const void* g, void* s) {
    __builtin_amdgcn_global_load_lds((const __attribute__((address_space(1))) void*)g,
                                     (__attribute__((address_space(3))) void*)s,
                                     16, 0, 0);
}

// ---------------------------------------------------------------------------
// Layouts (fragment-major, shared by producers and GEMM):
//   xqS: [mtile 32][kt 64][c 4][row 256][16B]   c = ksub*2+kh
//   wtS: [ntile 64][kt 64][c 4][col 256][16B]
// ---------------------------------------------------------------------------

// Kernel 1: weight [K=4096][N=16384] int32 -> wtS (narrow + transpose + tile)
__global__ __launch_bounds__(256) void transpose_kernel(const int* __restrict__ w,
                                                        uint8_t* __restrict__ wtS) {
    __shared__ uint8_t tile[64][68];
    const int t  = threadIdx.x;
    const int nb = blockIdx.x * 64;
    const int kt = blockIdx.y;          // K-tile = 64 k-rows
    const int kb = kt * 64;

#pragma unroll
    for (int p = 0; p < 4; ++p) {
        const int r = p * 16 + (t >> 4);
        const int c4 = t & 15;
        int4 u = *reinterpret_cast<const int4*>(w + (size_t)(kb + r) * OUT_F + nb + c4 * 4);
        uint32_t packed = (uint32_t)(u.x & 255) | ((uint32_t)(u.y & 255) << 8)
                        | ((uint32_t)(u.z & 255) << 16) | ((uint32_t)(u.w & 255) << 24);
        *reinterpret_cast<uint32_t*>(&tile[r][c4 * 4]) = packed;
    }
    __syncthreads();

    const int col = t >> 2;             // 0..63
    const int c   = t & 3;              // ksub*2+kh
    uint4 o;
    uint32_t* op = reinterpret_cast<uint32_t*>(&o);
#pragma unroll
    for (int j = 0; j < 4; ++j) {
        const int kk = c * 16 + j * 4;
        op[j] = (uint32_t)tile[kk][col] | ((uint32_t)tile[kk + 1][col] << 8)
              | ((uint32_t)tile[kk + 2][col] << 16) | ((uint32_t)tile[kk + 3][col] << 24);
    }
    const int ntile = nb >> 8;
    const int colg  = (nb & 255) + col;
    *reinterpret_cast<uint4*>(wtS + (((size_t)ntile * NKT + kt) * 4 + c) * 4096 + colg * 16) = o;
}

// Kernel 2: per-row dynamic quant -> xqS (fragment-major) + xs
__global__ __launch_bounds__(256) void quant_kernel(const float* __restrict__ x,
                                                    uint8_t* __restrict__ xqS,
                                                    float* __restrict__ xs) {
    const int t = threadIdx.x;
    const int w = t >> 6, l = t & 63;
    const int half = l >> 5, lh = l & 31;
    const int m = blockIdx.x * 8 + w * 2 + half;
    const float* xr = x + (size_t)m * IN_F;

    float am = 0.0f;
#pragma unroll 8
    for (int jj = 0; jj < 32; ++jj) {
        float4 v = reinterpret_cast<const float4*>(xr)[jj * 32 + lh];
        am = fmaxf(am, fmaxf(fmaxf(fabsf(v.x), fabsf(v.y)),
                             fmaxf(fabsf(v.z), fabsf(v.w))));
    }
#pragma unroll
    for (int off = 16; off; off >>= 1) am = fmaxf(am, __shfl_xor(am, off));

    const float scale = fmaxf(am / 127.0f, 1e-12f);
    if (lh == 0) xs[m] = scale;

    const int mtile = m >> 8, mrow = m & 255;
    uint8_t* ob = xqS + (size_t)mtile * (NKT * 16384) + (size_t)mrow * 16;
#pragma unroll
    for (int j = 0; j < 8; ++j) {
        const int k0 = lh * 128 + j * 16;
        const float4* vp = reinterpret_cast<const float4*>(xr + k0);
        uint4 pk;
        uint32_t* pp = reinterpret_cast<uint32_t*>(&pk);
#pragma unroll
        for (int q = 0; q < 4; ++q) {
            float4 v = vp[q];
            float r0 = fminf(127.f, fmaxf(-128.f, rintf(v.x / scale)));
            float r1 = fminf(127.f, fmaxf(-128.f, rintf(v.y / scale)));
            float r2 = fminf(127.f, fmaxf(-128.f, rintf(v.z / scale)));
            float r3 = fminf(127.f, fmaxf(-128.f, rintf(v.w / scale)));
            pp[q] = ((uint32_t)((int)r0 & 255)) | ((uint32_t)((int)r1 & 255) << 8)
                  | ((uint32_t)((int)r2 & 255) << 16) | ((uint32_t)((int)r3 & 255) << 24);
        }
        const int ktk = k0 >> 6;
        const int c   = (k0 >> 4) & 3;
        *reinterpret_cast<uint4*>(ob + ((size_t)ktk * 4 + c) * 4096) = pk;
    }
}

// ---------------------------------------------------------------------------
// Kernel 3: int8 GEMM, 256x256 tile, 8 waves (2Mx4N), round-8 schedule.
// A: quad-buffered LDS (64KB), depth-3 gload_lds staging, reg-dbuf frags.
// B: global (L2-resident) -> VGPR at DEPTH-2 (B(kt+2) issued after its
// set's last use; compiler-counted vmcnt covers the reg RAW). LDS pipe
// drops to 64 reads + 16KB writes (~960cyc) < MFMA 1170cyc.
// Manual vmcnt ledger (incl. B): steady 12, tails 10 -> 8.
// ---------------------------------------------------------------------------
#define GEMM_STEP(KT, BSET)                                                           \
    {                                                                                 \
        const int q  = ((KT) & 3) * 16384;                                            \
        const int q1 = (((KT) + 1) & 3) * 16384;                                      \
        const int q3 = (((KT) + 3) & 3) * 16384;                                      \
        _Pragma("unroll")  /* 1. ds_reads (KT, s=1) -> f1, overlap MFMA f0 */         \
        for (int mr = 0; mr < 4; ++mr)                                                \
            af1[mr] = *reinterpret_cast<const int32x4*>(ldsA + q + 8192 + aRd0 + mr * 512); \
        if ((KT) < NKT - 3) {  /* 2. stage A tile KT+3 (WAR freed last barrier) */    \
            const size_t src3 = (size_t)((KT) + 3) * 16384;                           \
            _Pragma("unroll")                                                         \
            for (int L = 0; L < 2; ++L)                                               \
                gload_lds16(aBase + src3 + L * 8192 + t16, ldsA + q3 + L * 8192 + wofs); \
        }                                                                             \
        /* 3. MFMA f0 */                                                              \
        __builtin_amdgcn_s_setprio(1);                                                \
        _Pragma("unroll")                                                             \
        for (int mr = 0; mr < 4; ++mr) {                                              \
            acc[mr][0] = __builtin_amdgcn_mfma_i32_32x32x32_i8(af0[mr], BSET[0], acc[mr][0], 0, 0, 0); \
            acc[mr][1] = __builtin_amdgcn_mfma_i32_32x32x32_i8(af0[mr], BSET[1], acc[mr][1], 0, 0, 0); \
        }                                                                             \
        __builtin_amdgcn_s_setprio(0);                                                \
        if ((KT) < NKT - 1) {                                                         \
            /* 4. drain own ds_reads (WAR across barrier) + counted vmcnt:     */     \
            /* queue: Ast(KT+1)2,B(KT)4,Ast(KT+2)2,B(KT+1)4,[Ast(KT+3)2] */           \
            asm volatile("s_waitcnt lgkmcnt(0)" ::: "memory");                        \
            if ((KT) < NKT - 3)       asm volatile("s_waitcnt vmcnt(12)" ::: "memory"); \
            else if ((KT) == NKT - 3) asm volatile("s_waitcnt vmcnt(10)" ::: "memory"); \
            else                      asm volatile("s_waitcnt vmcnt(8)" ::: "memory");  \
            __builtin_amdgcn_s_barrier();                                             \
            __builtin_amdgcn_sched_barrier(0);                                        \
            _Pragma("unroll")  /* 5. ds_reads (KT+1, s=0) -> f0, overlap MFMA f1 */   \
            for (int mr = 0; mr < 4; ++mr)                                            \
                af0[mr] = *reinterpret_cast<const int32x4*>(ldsA + q1 + aRd0 + mr * 512); \
        }                                                                             \
        /* 6. MFMA f1 */                                                              \
        __builtin_amdgcn_s_setprio(1);                                                \
        _Pragma("unroll")                                                             \
        for (int mr = 0; mr < 4; ++mr) {                                              \
            acc[mr][0] = __builtin_amdgcn_mfma_i32_32x32x32_i8(af1[mr], BSET[2], acc[mr][0], 0, 0, 0); \
            acc[mr][1] = __builtin_amdgcn_mfma_i32_32x32x32_i8(af1[mr], BSET[3], acc[mr][1], 0, 0, 0); \
        }                                                                             \
        __builtin_amdgcn_s_setprio(0);                                                \
        if ((KT) < NKT - 2) {  /* 7. reload BSET with B(KT+2) (reg WAR: after use) */ \
            const uint8_t* bsrc = bBase + (size_t)((KT) + 2) * 16384 + bGo;           \
            BSET[0] = *reinterpret_cast<const int32x4*>(bsrc);                        \
            BSET[1] = *reinterpret_cast<const int32x4*>(bsrc + 512);                  \
            BSET[2] = *reinterpret_cast<const int32x4*>(bsrc + 8192);                 \
            BSET[3] = *reinterpret_cast<const int32x4*>(bsrc + 8704);                 \
        }                                                                             \
    }

__global__ __launch_bounds__(512, 2) void gemm_kernel(const uint8_t* __restrict__ xqS,
                                                      const uint8_t* __restrict__ wtS,
                                                      const float* __restrict__ xs,
                                                      const float* __restrict__ wsc,
                                                      const float* __restrict__ bias,
                                                      float* __restrict__ out) {
    __shared__ uint8_t ldsA[65536];   // 4 bufs * 16KB (A only)

    const int t    = threadIdx.x;
    const int lane = t & 63;
    const int wid  = t >> 6;
    const int wm   = wid >> 2, wn = wid & 3;   // wave tile: 128 rows x 64 cols

    // XCD-aware mapping (round 8: FETCH 1.08GB -> 394MB, keep):
    const int xcd = blockIdx.x & 7;
    const int i   = blockIdx.x >> 3;           // 0..255 local on this XCD
    const int mt  = xcd * 4 + (i & 3);         // 0..31
    const int nt  = i >> 2;                    // 0..63

    const uint8_t* aBase = xqS + (size_t)mt * (NKT * 16384);
    const uint8_t* bBase = wtS + (size_t)nt * (NKT * 16384);
    const int t16  = t * 16;
    const int wofs = wid * 1024;

    const int aRd0 = (lane >> 5) * 4096 + wm * 2048 + (lane & 31) * 16;
    const int bGo  = (lane >> 5) * 4096 + wn * 1024 + (lane & 31) * 16;

    int32x16 acc[4][2] = {};
    int32x4 af0[4], af1[4], bE[4], bO[4];

    // prologue: stage A tiles 0,1,2; B(0)->bE, B(1)->bO
#pragma unroll
    for (int tt = 0; tt < 3; ++tt)
#pragma unroll
        for (int L = 0; L < 2; ++L)
            gload_lds16(aBase + tt * 16384 + L * 8192 + t16, ldsA + tt * 16384 + L * 8192 + wofs);
    {
        const uint8_t* b0 = bBase + bGo;
        const uint8_t* b1 = bBase + 16384 + bGo;
        bE[0] = *reinterpret_cast<const int32x4*>(b0);
        bE[1] = *reinterpret_cast<const int32x4*>(b0 + 512);
        bE[2] = *reinterpret_cast<const int32x4*>(b0 + 8192);
        bE[3] = *reinterpret_cast<const int32x4*>(b0 + 8704);
        bO[0] = *reinterpret_cast<const int32x4*>(b1);
        bO[1] = *reinterpret_cast<const int32x4*>(b1 + 512);
        bO[2] = *reinterpret_cast<const int32x4*>(b1 + 8192);
        bO[3] = *reinterpret_cast<const int32x4*>(b1 + 8704);
    }
    // queue: Ast0(2) Ast1(2) Ast2(2) B0(4) B1(4) = 14 -> retire Ast0
    asm volatile("s_waitcnt vmcnt(12)" ::: "memory");
    __builtin_amdgcn_s_barrier();
    __builtin_amdgcn_sched_barrier(0);

    // fragments (tile 0, s=0) -> f0
#pragma unroll
    for (int mr = 0; mr < 4; ++mr)
        af0[mr] = *reinterpret_cast<const int32x4*>(ldsA + aRd0 + mr * 512);

    for (int kt2 = 0; kt2 < NKT; kt2 += 2) {
        GEMM_STEP(kt2,     bE);
        GEMM_STEP(kt2 + 1, bO);
    }

    // epilogue: C/D 32x32 layout: col = lane&31, row = (g&3)+8*(g>>2)+4*(lane>>5)
    const int row0 = mt * 256 + wm * 128;
    const int col0 = nt * 256 + wn * 64;
#pragma unroll
    for (int mr = 0; mr < 4; ++mr) {
        const int rbase = row0 + mr * 32 + 4 * (lane >> 5);
        float xsv[16];
#pragma unroll
        for (int g = 0; g < 16; ++g)
            xsv[g] = xs[rbase + (g & 3) + 8 * (g >> 2)];
#pragma unroll
        for (int nr = 0; nr < 2; ++nr) {
            const int n = col0 + nr * 32 + (lane & 31);
            const float ws_n = wsc[n];
            const float b_n  = bias[n];
#pragma unroll
            for (int g = 0; g < 16; ++g) {
                const int m = rbase + (g & 3) + 8 * (g >> 2);
                out[(size_t)m * OUT_F + n] = (float)acc[mr][nr][g] * xsv[g] * ws_n + b_n;
            }
        }
    }
}

// ---------------------------------------------------------------------------
extern "C" void kernel_launch(void* const* d_in, const int* in_sizes, int n_in,
                              void* d_out, int out_size, void* d_ws, size_t ws_size,
                              hipStream_t stream) {
    const float* x    = (const float*)d_in[0];
    const int*   wq   = (const int*)d_in[1];     // int8 pushed as int32 [4096][16384]
    const float* wsc  = (const float*)d_in[2];
    const float* bias = (const float*)d_in[3];
    float* out = (float*)d_out;

    uint8_t* ws  = (uint8_t*)d_ws;
    uint8_t* wtS = ws;                                               // 64 MiB
    uint8_t* xqS = ws + (size_t)IN_F * OUT_F;                        // 32 MiB
    float*   xs  = (float*)(ws + (size_t)IN_F * OUT_F + (size_t)NROWS * IN_F);

    transpose_kernel<<<dim3(OUT_F / 64, IN_F / 64), 256, 0, stream>>>(wq, wtS);
    quant_kernel<<<NROWS / 8, 256, 0, stream>>>(x, xqS, xs);
    gemm_kernel<<<(NROWS / 256) * (OUT_F / 256), 512, 0, stream>>>(xqS, wtS, xs, wsc, bias, out);
}